// Round 11
// baseline (260.606 us; speedup 1.0000x reference)
//
#include <hip/hip_runtime.h>

// AutoregressiveLSTM: B=16384, T=100, HID=10, IN=OUT=4, P=5, Tp=96.
// Round 11 = Round 10 + compile fix (cvt_pkrtz returns __fp16x2; bit_cast to
// _Float16x2 for fdot2). Theory unchanged:
// (1) all dot products via v_dot2_f32_f16 (full-rate: 2 MAC/2cy vs pk_fma's
// 2 MAC/4cy -> halves MAC issue cost; f32 accumulate, no horizontal adds);
// (2) TWO batches per lane: per-lane weights, LDS-exchange latency and loop
// overhead amortized 2x, and two independent chains give in-wave ILP.
// Mapping: 10 lanes/group (lane u owns gate rows u,u+10,u+20,u+30), 6 groups
// per 64-thread block, 2 batches/group -> 12 batches/block, 1366 blocks.
// R5 algebra: all cells use folded W_comb = W_hh + W_ih@W_lin; main cell adds
// rank-4 correction wih@(x - y_prev), y_prev = y[t-1][p=0] from s_y.
// c and activations stay f32; only dot INPUTS are f16.

#define HIDN 10
#define INPN 4
#define OUTN 4
#define PN   5
#define TN   100
#define TPN  96
#define BN   16384
#define GPB  12   // batches per 64-thread block (6 groups x 2)

typedef float v2f __attribute__((ext_vector_type(2)));
typedef _Float16 h2v __attribute__((ext_vector_type(2)));

#define PIN(x) asm volatile("" : "+v"(x))

__device__ __forceinline__ float rcpf_(float v) { return __builtin_amdgcn_rcpf(v); }
__device__ __forceinline__ float e2_(float v)   { return __builtin_amdgcn_exp2f(v); }
// pre-scaled by log2(e):  sigmoid(x) = 1/(1+2^(-g))
__device__ __forceinline__ float sig2_(float g)  { return rcpf_(1.0f + e2_(-g)); }
// pre-scaled by 2*log2(e): tanh(x) = 1 - 2/(1+2^g)
__device__ __forceinline__ float tanh2_(float g) { return fmaf(-2.0f, rcpf_(1.0f + e2_(g)), 1.0f); }
__device__ __forceinline__ h2v   pk_(float a, float b) {
    return __builtin_bit_cast(h2v, __builtin_amdgcn_cvt_pkrtz(a, b));
}
__device__ __forceinline__ float dot2_(h2v a, h2v b, float c) {
    return __builtin_amdgcn_fdot2(a, b, c, false);
}

#define K2L2E 2.88539008177792681472f  // 2*log2(e), for tanh(c)

__global__ __launch_bounds__(64, 4) void lstm_ar_kernel(
    const float* __restrict__ x,      // [B, T, IN]
    const float* __restrict__ W_ih,   // [40, 4]
    const float* __restrict__ W_hh,   // [40, 10]
    const float* __restrict__ b_ih,   // [40]
    const float* __restrict__ b_hh,   // [40]
    const float* __restrict__ W_lin,  // [4, 10]
    const float* __restrict__ b_lin,  // [4]
    float* __restrict__ out)          // [B*Tp*P*OUT] ++ [B*HID]
{
    // h bank: [group][batch][row p][12 floats]; f32 (cvt to f16 at consumers).
    __shared__ __align__(16) float s_h[6][2][PN][12];
    __shared__ __align__(16) float s_y[6][2][4];     // y[t-1][p=0] per batch

    const int wl  = threadIdx.x;      // 0..63
    const int grp = wl / 10;          // 0..5 valid, 6 = idle lanes 60-63
    const int u   = wl - grp * 10;
    const int b0  = ((int)blockIdx.x * 6 + grp) * 2;
    if (grp >= 6 || b0 >= BN) return;

    // ---- fold weights in f32, pack to f16 (rows u,u+10,u+20,u+30 = i,f,g,o) ----
    const float L2E = 1.44269504088896340736f;
    const float rs[4] = { L2E, L2E, 2.0f * L2E, L2E };

    h2v  wc16[4][5];    // scaled W_comb rows (ALL cells)
    h2v  wih16[4][2];   // scaled W_ih rows (main-cell rank-4 correction)
    float br[4];        // scaled folded bias (f32 accumulator seed)
    #pragma unroll
    for (int r = 0; r < 4; ++r) {
        const int j = u + r * 10;
        float wihr[INPN];
        #pragma unroll
        for (int q = 0; q < INPN; ++q) wihr[q] = W_ih[j * INPN + q];
        float brr = b_ih[j] + b_hh[j];
        #pragma unroll
        for (int q = 0; q < INPN; ++q) brr += wihr[q] * b_lin[q];
        float wcf[HIDN];
        #pragma unroll
        for (int k = 0; k < HIDN; ++k) {
            float wck = W_hh[j * HIDN + k];
            #pragma unroll
            for (int q = 0; q < INPN; ++q) wck += wihr[q] * W_lin[q * HIDN + k];
            wcf[k] = wck * rs[r];
        }
        #pragma unroll
        for (int k2 = 0; k2 < 5; ++k2) wc16[r][k2] = pk_(wcf[2 * k2], wcf[2 * k2 + 1]);
        wih16[r][0] = pk_(wihr[0] * rs[r], wihr[1] * rs[r]);
        wih16[r][1] = pk_(wihr[2] * rs[r], wihr[3] * rs[r]);
        br[r] = brr * rs[r];
    }

    // ---- y weights: lane u -> y[pmine][opair..opair+1] ----
    const int pmine = u >> 1;
    const int opair = (u & 1) * 2;
    h2v yl16[2][5];
    #pragma unroll
    for (int k2 = 0; k2 < 5; ++k2) {
        yl16[0][k2] = pk_(W_lin[opair * HIDN + 2 * k2],       W_lin[opair * HIDN + 2 * k2 + 1]);
        yl16[1][k2] = pk_(W_lin[(opair + 1) * HIDN + 2 * k2], W_lin[(opair + 1) * HIDN + 2 * k2 + 1]);
    }
    float yb0 = b_lin[opair];
    float yb1 = b_lin[opair + 1];

    // ---- pin weights ----
    #pragma unroll
    for (int r = 0; r < 4; ++r) {
        #pragma unroll
        for (int k = 0; k < 5; ++k) PIN(wc16[r][k]);
        PIN(wih16[r][0]); PIN(wih16[r][1]); PIN(br[r]);
    }
    #pragma unroll
    for (int k = 0; k < 5; ++k) { PIN(yl16[0][k]); PIN(yl16[1][k]); }
    PIN(yb0); PIN(yb1);

    // ---- init state ----
    float c[2] = { 0.0f, 0.0f };
    h2v hm16[2][5];
    #pragma unroll
    for (int b = 0; b < 2; ++b)
        #pragma unroll
        for (int k = 0; k < 5; ++k) hm16[b][k] = pk_(0.0f, 0.0f);

    if (u < 4) { s_y[grp][0][u] = b_lin[u]; s_y[grp][1][u] = b_lin[u]; }
    __builtin_amdgcn_wave_barrier();

    const float* xb0 = x + (long)b0 * TN * INPN;
    const float* xb1 = xb0 + TN * INPN;
    float* outp0 = out + (long)b0 * TPN * PN * OUTN;
    float* outp1 = outp0 + TPN * PN * OUTN;

    for (int t = 0; t < TPN; ++t) {
        const float4 xv0 = *(const float4*)(xb0 + t * INPN);
        const float4 xv1 = *(const float4*)(xb1 + t * INPN);

        // ---- MAIN (both batches): gates = wc@h + br + wih@(x - y_prev) ----
        {
            const float4 yp0 = *(const float4*)&s_y[grp][0][0];
            const float4 yp1 = *(const float4*)&s_y[grp][1][0];
            h2v dx[2][2];
            dx[0][0] = pk_(xv0.x - yp0.x, xv0.y - yp0.y);
            dx[0][1] = pk_(xv0.z - yp0.z, xv0.w - yp0.w);
            dx[1][0] = pk_(xv1.x - yp1.x, xv1.y - yp1.y);
            dx[1][1] = pk_(xv1.z - yp1.z, xv1.w - yp1.w);
            #pragma unroll
            for (int b = 0; b < 2; ++b) {
                float g[4];
                #pragma unroll
                for (int r = 0; r < 4; ++r) {
                    float a = br[r];
                    a = dot2_(wih16[r][0], dx[b][0], a);
                    a = dot2_(wih16[r][1], dx[b][1], a);
                    #pragma unroll
                    for (int k = 0; k < 5; ++k) a = dot2_(wc16[r][k], hm16[b][k], a);
                    g[r] = a;
                }
                float iv = sig2_(g[0]), fv = sig2_(g[1]), gv = tanh2_(g[2]), ov = sig2_(g[3]);
                c[b] = fmaf(fv, c[b], iv * gv);
                float hn = ov * tanh2_(c[b] * K2L2E);
                s_h[grp][b][0][u] = hn;
            }
        }
        __builtin_amdgcn_wave_barrier();
        #pragma unroll
        for (int b = 0; b < 2; ++b) {
            const v2f* hp = (const v2f*)&s_h[grp][b][0][0];
            #pragma unroll
            for (int k = 0; k < 5; ++k) { v2f p = hp[k]; hm16[b][k] = pk_(p.x, p.y); }
        }

        // ---- ROLLOUT p=1..4: gates = wc@h_{p-1} + br ----
        float cr[2] = { c[0], c[1] };
        h2v hr16[2][5];
        #pragma unroll
        for (int b = 0; b < 2; ++b)
            #pragma unroll
            for (int k = 0; k < 5; ++k) hr16[b][k] = hm16[b][k];
        #pragma unroll
        for (int p = 1; p < PN; ++p) {
            #pragma unroll
            for (int b = 0; b < 2; ++b) {
                float g[4];
                #pragma unroll
                for (int r = 0; r < 4; ++r) {
                    float a = br[r];
                    #pragma unroll
                    for (int k = 0; k < 5; ++k) a = dot2_(wc16[r][k], hr16[b][k], a);
                    g[r] = a;
                }
                float iv = sig2_(g[0]), fv = sig2_(g[1]), gv = tanh2_(g[2]), ov = sig2_(g[3]);
                cr[b] = fmaf(fv, cr[b], iv * gv);
                float hn = ov * tanh2_(cr[b] * K2L2E);
                s_h[grp][b][p][u] = hn;
            }
            __builtin_amdgcn_wave_barrier();
            if (p < PN - 1) {
                #pragma unroll
                for (int b = 0; b < 2; ++b) {
                    const v2f* hp = (const v2f*)&s_h[grp][b][p][0];
                    #pragma unroll
                    for (int k = 0; k < 5; ++k) { v2f q = hp[k]; hr16[b][k] = pk_(q.x, q.y); }
                }
            }
        }

        // ---- Y: lane u -> y[t][pmine][opair..opair+1] for both batches ----
        #pragma unroll
        for (int b = 0; b < 2; ++b) {
            const v2f* hq = (const v2f*)&s_h[grp][b][pmine][0];
            h2v hh[5];
            #pragma unroll
            for (int k = 0; k < 5; ++k) { v2f q = hq[k]; hh[k] = pk_(q.x, q.y); }
            float y0 = yb0, y1 = yb1;
            #pragma unroll
            for (int k = 0; k < 5; ++k) {
                y0 = dot2_(yl16[0][k], hh[k], y0);
                y1 = dot2_(yl16[1][k], hh[k], y1);
            }
            float2 yv; yv.x = y0; yv.y = y1;
            *(float2*)((b ? outp1 : outp0) + t * PN * OUTN + 2 * u) = yv;
            if (u < 2) *(float2*)&s_y[grp][b][2 * u] = yv;  // pmine==0 feeds next MAIN
        }
        __builtin_amdgcn_wave_barrier();
    }

    // ---- final cell state c: [1, B, HID] appended after final_output ----
    out[(long)BN * TPN * PN * OUTN + (long)b0 * HIDN + u]       = c[0];
    out[(long)BN * TPN * PN * OUTN + (long)(b0 + 1) * HIDN + u] = c[1];
}

extern "C" void kernel_launch(void* const* d_in, const int* in_sizes, int n_in,
                              void* d_out, int out_size, void* d_ws, size_t ws_size,
                              hipStream_t stream) {
    const float* x     = (const float*)d_in[0];
    const float* W_ih  = (const float*)d_in[1];
    const float* W_hh  = (const float*)d_in[2];
    const float* b_ih  = (const float*)d_in[3];
    const float* b_hh  = (const float*)d_in[4];
    const float* W_lin = (const float*)d_in[5];
    const float* b_lin = (const float*)d_in[6];
    float* out = (float*)d_out;

    const int grid = (BN + GPB - 1) / GPB;  // 1366 blocks of 64 threads
    lstm_ar_kernel<<<grid, 64, 0, stream>>>(x, W_ih, W_hh, b_ih, b_hh, W_lin, b_lin, out);
}

// Round 12
// 198.496 us; speedup vs baseline: 1.3129x; 1.3129x over previous
//
#include <hip/hip_runtime.h>

// AutoregressiveLSTM: B=16384, T=100, HID=10, IN=OUT=4, P=5, Tp=96.
// Round 12 = R5 structure (best measured: 10 lanes/batch, 6 groups/wave,
// 4 waves/block, 683 blocks -> 2.67 waves/SIMD; simple barrier loop; folded
// W_comb for ALL cells + rank-4 correction wih@(x - y_prev) for MAIN)
// + R11 arithmetic (v_dot2_f32_f16: 2 MAC/2cy, f32 accumulate, no horizontal
// adds; f16 on dot INPUTS only -- c, gates, activations stay f32; absmax
// 0.0078 proven in R11). h stays f32 in LDS; consumers cvt_pkrtz on read.

#define HIDN 10
#define INPN 4
#define OUTN 4
#define PN   5
#define TN   100
#define TPN  96
#define BN   16384
#define GPB  24   // batches per 256-thread block

typedef float v2f __attribute__((ext_vector_type(2)));
typedef _Float16 h2v __attribute__((ext_vector_type(2)));

#define PIN(x) asm volatile("" : "+v"(x))

__device__ __forceinline__ float rcpf_(float v) { return __builtin_amdgcn_rcpf(v); }
__device__ __forceinline__ float e2_(float v)   { return __builtin_amdgcn_exp2f(v); }
// pre-scaled by log2(e):  sigmoid(x) = 1/(1+2^(-g))
__device__ __forceinline__ float sig2_(float g)  { return rcpf_(1.0f + e2_(-g)); }
// pre-scaled by 2*log2(e): tanh(x) = 1 - 2/(1+2^g)
__device__ __forceinline__ float tanh2_(float g) { return fmaf(-2.0f, rcpf_(1.0f + e2_(g)), 1.0f); }
__device__ __forceinline__ h2v   pk_(float a, float b) {
    return __builtin_bit_cast(h2v, __builtin_amdgcn_cvt_pkrtz(a, b));
}
__device__ __forceinline__ float dot2_(h2v a, h2v b, float c) {
    return __builtin_amdgcn_fdot2(a, b, c, false);
}

#define K2L2E 2.88539008177792681472f  // 2*log2(e), for tanh(c)

__global__ __launch_bounds__(256, 3) void lstm_ar_kernel(
    const float* __restrict__ x,      // [B, T, IN]
    const float* __restrict__ W_ih,   // [40, 4]
    const float* __restrict__ W_hh,   // [40, 10]
    const float* __restrict__ b_ih,   // [40]
    const float* __restrict__ b_hh,   // [40]
    const float* __restrict__ W_lin,  // [4, 10]
    const float* __restrict__ b_lin,  // [4]
    float* __restrict__ out)          // [B*Tp*P*OUT] ++ [B*HID]
{
    // h rows: 12 floats (48B, 16B-aligned). f32; consumers cvt to f16 pairs.
    __shared__ __align__(16) float s_h[GPB][PN][12];
    __shared__ __align__(16) float s_y[GPB][4];   // y[t-1][p=0] per slot

    const int tid = threadIdx.x;
    const int wid = tid >> 6;
    const int wl  = tid & 63;
    const int grp = wl / 10;
    const int u   = wl - grp * 10;
    const int slot  = wid * 6 + grp;
    const int batch = blockIdx.x * GPB + slot;
    if (grp >= 6 || batch >= BN) return;

    // ---- fold weights in f32, pack to f16 (rows u,u+10,u+20,u+30 = i,f,g,o) ----
    const float L2E = 1.44269504088896340736f;
    const float rs[4] = { L2E, L2E, 2.0f * L2E, L2E };

    h2v  wc16[4][5];    // scaled W_comb rows = W_hh + W_ih@W_lin (ALL cells)
    h2v  wih16[4][2];   // scaled W_ih rows (main-cell rank-4 correction)
    float br[4];        // scaled folded bias (f32 accumulator seed)
    #pragma unroll
    for (int r = 0; r < 4; ++r) {
        const int j = u + r * 10;
        float wihr[INPN];
        #pragma unroll
        for (int q = 0; q < INPN; ++q) wihr[q] = W_ih[j * INPN + q];
        float brr = b_ih[j] + b_hh[j];
        #pragma unroll
        for (int q = 0; q < INPN; ++q) brr += wihr[q] * b_lin[q];
        float wcf[HIDN];
        #pragma unroll
        for (int k = 0; k < HIDN; ++k) {
            float wck = W_hh[j * HIDN + k];
            #pragma unroll
            for (int q = 0; q < INPN; ++q) wck += wihr[q] * W_lin[q * HIDN + k];
            wcf[k] = wck * rs[r];
        }
        #pragma unroll
        for (int k2 = 0; k2 < 5; ++k2) wc16[r][k2] = pk_(wcf[2 * k2], wcf[2 * k2 + 1]);
        wih16[r][0] = pk_(wihr[0] * rs[r], wihr[1] * rs[r]);
        wih16[r][1] = pk_(wihr[2] * rs[r], wihr[3] * rs[r]);
        br[r] = brr * rs[r];
    }

    // ---- y weights: lane u -> y[pmine][opair..opair+1] ----
    const int pmine = u >> 1;
    const int opair = (u & 1) * 2;
    h2v yl16[2][5];
    #pragma unroll
    for (int k2 = 0; k2 < 5; ++k2) {
        yl16[0][k2] = pk_(W_lin[opair * HIDN + 2 * k2],       W_lin[opair * HIDN + 2 * k2 + 1]);
        yl16[1][k2] = pk_(W_lin[(opair + 1) * HIDN + 2 * k2], W_lin[(opair + 1) * HIDN + 2 * k2 + 1]);
    }
    float yb0 = b_lin[opair];
    float yb1 = b_lin[opair + 1];

    // ---- pin weights (defeat re-load/remat inside the loop) ----
    #pragma unroll
    for (int r = 0; r < 4; ++r) {
        #pragma unroll
        for (int k = 0; k < 5; ++k) PIN(wc16[r][k]);
        PIN(wih16[r][0]); PIN(wih16[r][1]); PIN(br[r]);
    }
    #pragma unroll
    for (int k = 0; k < 5; ++k) { PIN(yl16[0][k]); PIN(yl16[1][k]); }
    PIN(yb0); PIN(yb1);

    // ---- init recurrent state: h = 0 (row 0), y_prev = b_lin ----
    s_h[slot][0][u] = 0.0f;
    if (u < 4) s_y[slot][u] = b_lin[u];
    __builtin_amdgcn_wave_barrier();

    const float* xb   = x + (long)batch * TN * INPN;
    float*       outb = out + (long)batch * TPN * PN * OUTN;

    float cm = 0.0f;
    float4 xcur = *(const float4*)xb;
    for (int t = 0; t < TPN; ++t) {
        float4 xnext = *(const float4*)(xb + (t + 1) * INPN);  // t+1 <= 96 < 100

        h2v h16[5];
        float g[4];

        // ---- MAIN: gates = wc@h + br + wih@(x - y_prev) ----
        {
            float4 yp = *(const float4*)&s_y[slot][0];
            const v2f* hp = (const v2f*)&s_h[slot][0][0];
            #pragma unroll
            for (int k = 0; k < 5; ++k) { v2f q = hp[k]; h16[k] = pk_(q.x, q.y); }
            h2v dx0 = pk_(xcur.x - yp.x, xcur.y - yp.y);
            h2v dx1 = pk_(xcur.z - yp.z, xcur.w - yp.w);
            #pragma unroll
            for (int r = 0; r < 4; ++r) {
                float a = br[r];
                a = dot2_(wih16[r][0], dx0, a);
                a = dot2_(wih16[r][1], dx1, a);
                #pragma unroll
                for (int k = 0; k < 5; ++k) a = dot2_(wc16[r][k], h16[k], a);
                g[r] = a;
            }
            float iv = sig2_(g[0]), fv = sig2_(g[1]), gv = tanh2_(g[2]), ov = sig2_(g[3]);
            cm = fmaf(fv, cm, iv * gv);
            float hn = ov * tanh2_(cm * K2L2E);
            s_h[slot][0][u] = hn;   // h_t overwrites h_{t-1}
        }
        __builtin_amdgcn_wave_barrier();

        // ---- ROLLOUT p=1..4: gates = wc@h_{p-1} + br ----
        float cr = cm;
        #pragma unroll
        for (int p = 1; p < PN; ++p) {
            const v2f* hp = (const v2f*)&s_h[slot][p - 1][0];
            #pragma unroll
            for (int k = 0; k < 5; ++k) { v2f q = hp[k]; h16[k] = pk_(q.x, q.y); }
            #pragma unroll
            for (int r = 0; r < 4; ++r) {
                float a = br[r];
                #pragma unroll
                for (int k = 0; k < 5; ++k) a = dot2_(wc16[r][k], h16[k], a);
                g[r] = a;
            }
            float iv = sig2_(g[0]), fv = sig2_(g[1]), gv = tanh2_(g[2]), ov = sig2_(g[3]);
            cr = fmaf(fv, cr, iv * gv);
            float hn = ov * tanh2_(cr * K2L2E);
            s_h[slot][p][u] = hn;
            __builtin_amdgcn_wave_barrier();
        }

        // ---- Y: lane u -> y[t][pmine][opair..opair+1] ----
        {
            const v2f* hq = (const v2f*)&s_h[slot][pmine][0];
            h2v hh[5];
            #pragma unroll
            for (int k = 0; k < 5; ++k) { v2f q = hq[k]; hh[k] = pk_(q.x, q.y); }
            float y0 = yb0, y1 = yb1;
            #pragma unroll
            for (int k = 0; k < 5; ++k) {
                y0 = dot2_(yl16[0][k], hh[k], y0);
                y1 = dot2_(yl16[1][k], hh[k], y1);
            }
            float2 yv; yv.x = y0; yv.y = y1;
            *(float2*)(outb + t * PN * OUTN + 2 * u) = yv;
            // lanes 0-1 (pmine==0) mirror y[t][p=0] into s_y for next MAIN
            if (u < 2) *(float2*)&s_y[slot][2 * u] = yv;
        }
        __builtin_amdgcn_wave_barrier();

        xcur = xnext;
    }

    // ---- final cell state c: [1, B, HID] appended after final_output ----
    out[(long)BN * TPN * PN * OUTN + (long)batch * HIDN + u] = cm;
}

extern "C" void kernel_launch(void* const* d_in, const int* in_sizes, int n_in,
                              void* d_out, int out_size, void* d_ws, size_t ws_size,
                              hipStream_t stream) {
    const float* x     = (const float*)d_in[0];
    const float* W_ih  = (const float*)d_in[1];
    const float* W_hh  = (const float*)d_in[2];
    const float* b_ih  = (const float*)d_in[3];
    const float* b_hh  = (const float*)d_in[4];
    const float* W_lin = (const float*)d_in[5];
    const float* b_lin = (const float*)d_in[6];
    float* out = (float*)d_out;

    const int grid = (BN + GPB - 1) / GPB;  // 683 blocks of 256 threads
    lstm_ar_kernel<<<grid, 256, 0, stream>>>(x, W_ih, W_hh, b_ih, b_hh, W_lin, b_lin, out);
}

// Round 13
// 195.382 us; speedup vs baseline: 1.3338x; 1.0159x over previous
//
#include <hip/hip_runtime.h>

// AutoregressiveLSTM: B=16384, T=100, HID=10, IN=OUT=4, P=5, Tp=96.
// Round 13 = Round 12 + IN-LOOP re-PIN of all weights. R12's setup-time PIN
// left loop-carried weight copies in AGPRs (VGPR_Count=40 < 44-reg weight set)
// -> every fdot2 weight operand cost a v_accvgpr_read (~490 cy/step, the gap
// between static 930 and back-solved 1418 cy/wave-step). Re-asserting "+v" on
// all 44 weight values at each loop-body top forces arch-VGPR residency inside
// the loop (worst case: one copy-pair per weight per step = ~88 cy, 5x less).
// Structure: R5 mapping (10 lanes/batch, 6 grp/wave, 4 waves, 683 blocks,
// 2.67 waves/SIMD); folded W_comb all cells + rank-4 MAIN correction; fdot2.

#define HIDN 10
#define INPN 4
#define OUTN 4
#define PN   5
#define TN   100
#define TPN  96
#define BN   16384
#define GPB  24   // batches per 256-thread block

typedef float v2f __attribute__((ext_vector_type(2)));
typedef _Float16 h2v __attribute__((ext_vector_type(2)));

__device__ __forceinline__ float rcpf_(float v) { return __builtin_amdgcn_rcpf(v); }
__device__ __forceinline__ float e2_(float v)   { return __builtin_amdgcn_exp2f(v); }
// pre-scaled by log2(e):  sigmoid(x) = 1/(1+2^(-g))
__device__ __forceinline__ float sig2_(float g)  { return rcpf_(1.0f + e2_(-g)); }
// pre-scaled by 2*log2(e): tanh(x) = 1 - 2/(1+2^g)
__device__ __forceinline__ float tanh2_(float g) { return fmaf(-2.0f, rcpf_(1.0f + e2_(g)), 1.0f); }
__device__ __forceinline__ h2v   pk_(float a, float b) {
    return __builtin_bit_cast(h2v, __builtin_amdgcn_cvt_pkrtz(a, b));
}
__device__ __forceinline__ float dot2_(h2v a, h2v b, float c) {
    return __builtin_amdgcn_fdot2(a, b, c, false);
}

#define K2L2E 2.88539008177792681472f  // 2*log2(e), for tanh(c)

__global__ __launch_bounds__(256, 3) void lstm_ar_kernel(
    const float* __restrict__ x,      // [B, T, IN]
    const float* __restrict__ W_ih,   // [40, 4]
    const float* __restrict__ W_hh,   // [40, 10]
    const float* __restrict__ b_ih,   // [40]
    const float* __restrict__ b_hh,   // [40]
    const float* __restrict__ W_lin,  // [4, 10]
    const float* __restrict__ b_lin,  // [4]
    float* __restrict__ out)          // [B*Tp*P*OUT] ++ [B*HID]
{
    // h rows: 12 floats (48B, 16B-aligned). f32; consumers cvt to f16 pairs.
    __shared__ __align__(16) float s_h[GPB][PN][12];
    __shared__ __align__(16) float s_y[GPB][4];   // y[t-1][p=0] per slot

    const int tid = threadIdx.x;
    const int wid = tid >> 6;
    const int wl  = tid & 63;
    const int grp = wl / 10;
    const int u   = wl - grp * 10;
    const int slot  = wid * 6 + grp;
    const int batch = blockIdx.x * GPB + slot;
    if (grp >= 6 || batch >= BN) return;

    // ---- fold weights in f32, pack to f16 (rows u,u+10,u+20,u+30 = i,f,g,o) ----
    const float L2E = 1.44269504088896340736f;
    const float rs[4] = { L2E, L2E, 2.0f * L2E, L2E };

    h2v  wc16[4][5];    // scaled W_comb rows = W_hh + W_ih@W_lin (ALL cells)
    h2v  wih16[4][2];   // scaled W_ih rows (main-cell rank-4 correction)
    float br[4];        // scaled folded bias (f32 accumulator seed)
    #pragma unroll
    for (int r = 0; r < 4; ++r) {
        const int j = u + r * 10;
        float wihr[INPN];
        #pragma unroll
        for (int q = 0; q < INPN; ++q) wihr[q] = W_ih[j * INPN + q];
        float brr = b_ih[j] + b_hh[j];
        #pragma unroll
        for (int q = 0; q < INPN; ++q) brr += wihr[q] * b_lin[q];
        float wcf[HIDN];
        #pragma unroll
        for (int k = 0; k < HIDN; ++k) {
            float wck = W_hh[j * HIDN + k];
            #pragma unroll
            for (int q = 0; q < INPN; ++q) wck += wihr[q] * W_lin[q * HIDN + k];
            wcf[k] = wck * rs[r];
        }
        #pragma unroll
        for (int k2 = 0; k2 < 5; ++k2) wc16[r][k2] = pk_(wcf[2 * k2], wcf[2 * k2 + 1]);
        wih16[r][0] = pk_(wihr[0] * rs[r], wihr[1] * rs[r]);
        wih16[r][1] = pk_(wihr[2] * rs[r], wihr[3] * rs[r]);
        br[r] = brr * rs[r];
    }

    // ---- y weights: lane u -> y[pmine][opair..opair+1] ----
    const int pmine = u >> 1;
    const int opair = (u & 1) * 2;
    h2v yl16[2][5];
    #pragma unroll
    for (int k2 = 0; k2 < 5; ++k2) {
        yl16[0][k2] = pk_(W_lin[opair * HIDN + 2 * k2],       W_lin[opair * HIDN + 2 * k2 + 1]);
        yl16[1][k2] = pk_(W_lin[(opair + 1) * HIDN + 2 * k2], W_lin[(opair + 1) * HIDN + 2 * k2 + 1]);
    }
    float yb0 = b_lin[opair];
    float yb1 = b_lin[opair + 1];

    // ---- init recurrent state: h = 0 (row 0), y_prev = b_lin ----
    s_h[slot][0][u] = 0.0f;
    if (u < 4) s_y[slot][u] = b_lin[u];
    __builtin_amdgcn_wave_barrier();

    const float* xb   = x + (long)batch * TN * INPN;
    float*       outb = out + (long)batch * TPN * PN * OUTN;

    float cm = 0.0f;
    float4 xcur = *(const float4*)xb;
    for (int t = 0; t < TPN; ++t) {
        // ---- IN-LOOP re-PIN: weights must be arch-VGPR-resident here ----
        asm volatile("" :
            "+v"(wc16[0][0]), "+v"(wc16[0][1]), "+v"(wc16[0][2]), "+v"(wc16[0][3]), "+v"(wc16[0][4]),
            "+v"(wc16[1][0]), "+v"(wc16[1][1]), "+v"(wc16[1][2]), "+v"(wc16[1][3]), "+v"(wc16[1][4]),
            "+v"(wc16[2][0]), "+v"(wc16[2][1]), "+v"(wc16[2][2]), "+v"(wc16[2][3]), "+v"(wc16[2][4]),
            "+v"(wc16[3][0]), "+v"(wc16[3][1]), "+v"(wc16[3][2]), "+v"(wc16[3][3]), "+v"(wc16[3][4]));
        asm volatile("" :
            "+v"(wih16[0][0]), "+v"(wih16[0][1]), "+v"(wih16[1][0]), "+v"(wih16[1][1]),
            "+v"(wih16[2][0]), "+v"(wih16[2][1]), "+v"(wih16[3][0]), "+v"(wih16[3][1]),
            "+v"(br[0]), "+v"(br[1]), "+v"(br[2]), "+v"(br[3]));
        asm volatile("" :
            "+v"(yl16[0][0]), "+v"(yl16[0][1]), "+v"(yl16[0][2]), "+v"(yl16[0][3]), "+v"(yl16[0][4]),
            "+v"(yl16[1][0]), "+v"(yl16[1][1]), "+v"(yl16[1][2]), "+v"(yl16[1][3]), "+v"(yl16[1][4]),
            "+v"(yb0), "+v"(yb1));

        float4 xnext = *(const float4*)(xb + (t + 1) * INPN);  // t+1 <= 96 < 100

        h2v h16[5];
        float g[4];

        // ---- MAIN: gates = wc@h + br + wih@(x - y_prev) ----
        {
            float4 yp = *(const float4*)&s_y[slot][0];
            const v2f* hp = (const v2f*)&s_h[slot][0][0];
            #pragma unroll
            for (int k = 0; k < 5; ++k) { v2f q = hp[k]; h16[k] = pk_(q.x, q.y); }
            h2v dx0 = pk_(xcur.x - yp.x, xcur.y - yp.y);
            h2v dx1 = pk_(xcur.z - yp.z, xcur.w - yp.w);
            #pragma unroll
            for (int r = 0; r < 4; ++r) {
                float a = br[r];
                a = dot2_(wih16[r][0], dx0, a);
                a = dot2_(wih16[r][1], dx1, a);
                #pragma unroll
                for (int k = 0; k < 5; ++k) a = dot2_(wc16[r][k], h16[k], a);
                g[r] = a;
            }
            float iv = sig2_(g[0]), fv = sig2_(g[1]), gv = tanh2_(g[2]), ov = sig2_(g[3]);
            cm = fmaf(fv, cm, iv * gv);
            float hn = ov * tanh2_(cm * K2L2E);
            s_h[slot][0][u] = hn;   // h_t overwrites h_{t-1}
        }
        __builtin_amdgcn_wave_barrier();

        // ---- ROLLOUT p=1..4: gates = wc@h_{p-1} + br ----
        float cr = cm;
        #pragma unroll
        for (int p = 1; p < PN; ++p) {
            const v2f* hp = (const v2f*)&s_h[slot][p - 1][0];
            #pragma unroll
            for (int k = 0; k < 5; ++k) { v2f q = hp[k]; h16[k] = pk_(q.x, q.y); }
            #pragma unroll
            for (int r = 0; r < 4; ++r) {
                float a = br[r];
                #pragma unroll
                for (int k = 0; k < 5; ++k) a = dot2_(wc16[r][k], h16[k], a);
                g[r] = a;
            }
            float iv = sig2_(g[0]), fv = sig2_(g[1]), gv = tanh2_(g[2]), ov = sig2_(g[3]);
            cr = fmaf(fv, cr, iv * gv);
            float hn = ov * tanh2_(cr * K2L2E);
            s_h[slot][p][u] = hn;
            __builtin_amdgcn_wave_barrier();
        }

        // ---- Y: lane u -> y[t][pmine][opair..opair+1] ----
        {
            const v2f* hq = (const v2f*)&s_h[slot][pmine][0];
            h2v hh[5];
            #pragma unroll
            for (int k = 0; k < 5; ++k) { v2f q = hq[k]; hh[k] = pk_(q.x, q.y); }
            float y0 = yb0, y1 = yb1;
            #pragma unroll
            for (int k = 0; k < 5; ++k) {
                y0 = dot2_(yl16[0][k], hh[k], y0);
                y1 = dot2_(yl16[1][k], hh[k], y1);
            }
            float2 yv; yv.x = y0; yv.y = y1;
            *(float2*)(outb + t * PN * OUTN + 2 * u) = yv;
            // lanes 0-1 (pmine==0) mirror y[t][p=0] into s_y for next MAIN
            if (u < 2) *(float2*)&s_y[slot][2 * u] = yv;
        }
        __builtin_amdgcn_wave_barrier();

        xcur = xnext;
    }

    // ---- final cell state c: [1, B, HID] appended after final_output ----
    out[(long)BN * TPN * PN * OUTN + (long)batch * HIDN + u] = cm;
}

extern "C" void kernel_launch(void* const* d_in, const int* in_sizes, int n_in,
                              void* d_out, int out_size, void* d_ws, size_t ws_size,
                              hipStream_t stream) {
    const float* x     = (const float*)d_in[0];
    const float* W_ih  = (const float*)d_in[1];
    const float* W_hh  = (const float*)d_in[2];
    const float* b_ih  = (const float*)d_in[3];
    const float* b_hh  = (const float*)d_in[4];
    const float* W_lin = (const float*)d_in[5];
    const float* b_lin = (const float*)d_in[6];
    float* out = (float*)d_out;

    const int grid = (BN + GPB - 1) / GPB;  // 683 blocks of 256 threads
    lstm_ar_kernel<<<grid, 256, 0, stream>>>(x, W_ih, W_hh, b_ih, b_hh, W_lin, b_lin, out);
}